// Round 2
// baseline (7454.690 us; speedup 1.0000x reference)
//
#include <hip/hip_runtime.h>
#include <cstddef>

#define B_ 256
#define T_ 128
#define F_ 256
#define H_ 512
#define C_ 10

// ---------------------------------------------------------------------------
// GEMM: Cout[M, 512] = A[M, K] @ W[512, K]^T + b1 + b2   (fp32, vector ALU)
// Tiles: BM=64, BN=128, BK=32; 256 threads; 4x8 micro-tile per thread.
// Row-local in M: output row m depends only on input row m.
// ---------------------------------------------------------------------------
template<int K>
__global__ __launch_bounds__(256) void gemm_bias_kernel(
    const float* __restrict__ A, const float* __restrict__ W,
    const float* __restrict__ b1, const float* __restrict__ b2,
    float* __restrict__ Cout)
{
    __shared__ alignas(16) float As[32][68];    // [k][m], pad 64->68
    __shared__ alignas(16) float Ws[32][132];   // [k][n], pad 128->132

    const int tid = threadIdx.x;
    const int m0 = blockIdx.x * 64;
    const int n0 = blockIdx.y * 128;
    const int tx = tid & 15;        // n dim: 16 threads * 8
    const int ty = tid >> 4;        // m dim: 16 threads * 4

    float acc[4][8];
#pragma unroll
    for (int i = 0; i < 4; i++)
#pragma unroll
        for (int j = 0; j < 8; j++) acc[i][j] = 0.f;

    for (int k0 = 0; k0 < K; k0 += 32) {
        // A tile: 64 rows x 32 k = 512 float4, 2 per thread, coalesced along k
#pragma unroll
        for (int i = 0; i < 2; i++) {
            int f = tid + 256 * i;
            int m = f >> 3, k4 = (f & 7) * 4;
            float4 v = *(const float4*)(A + (size_t)(m0 + m) * K + k0 + k4);
            As[k4 + 0][m] = v.x; As[k4 + 1][m] = v.y;
            As[k4 + 2][m] = v.z; As[k4 + 3][m] = v.w;
        }
        // W tile: 128 rows x 32 k = 1024 float4, 4 per thread
#pragma unroll
        for (int i = 0; i < 4; i++) {
            int f = tid + 256 * i;
            int n = f >> 3, k4 = (f & 7) * 4;
            float4 v = *(const float4*)(W + (size_t)(n0 + n) * K + k0 + k4);
            Ws[k4 + 0][n] = v.x; Ws[k4 + 1][n] = v.y;
            Ws[k4 + 2][n] = v.z; Ws[k4 + 3][n] = v.w;
        }
        __syncthreads();

#pragma unroll 8
        for (int kk = 0; kk < 32; kk++) {
            float4 a4 = *(const float4*)&As[kk][ty * 4];
            float4 w0 = *(const float4*)&Ws[kk][tx * 8];
            float4 w1 = *(const float4*)&Ws[kk][tx * 8 + 4];
            float a[4] = {a4.x, a4.y, a4.z, a4.w};
            float w[8] = {w0.x, w0.y, w0.z, w0.w, w1.x, w1.y, w1.z, w1.w};
#pragma unroll
            for (int i = 0; i < 4; i++)
#pragma unroll
                for (int j = 0; j < 8; j++)
                    acc[i][j] = fmaf(a[i], w[j], acc[i][j]);
        }
        __syncthreads();
    }

    float bias[8];
#pragma unroll
    for (int j = 0; j < 8; j++) {
        int n = n0 + tx * 8 + j;
        bias[j] = b1[n] + b2[n];
    }
#pragma unroll
    for (int i = 0; i < 4; i++) {
        int m = m0 + ty * 4 + i;
        float4 v0 = {acc[i][0] + bias[0], acc[i][1] + bias[1],
                     acc[i][2] + bias[2], acc[i][3] + bias[3]};
        float4 v1 = {acc[i][4] + bias[4], acc[i][5] + bias[5],
                     acc[i][6] + bias[6], acc[i][7] + bias[7]};
        *(float4*)(Cout + (size_t)m * H_ + n0 + tx * 8)     = v0;
        *(float4*)(Cout + (size_t)m * H_ + n0 + tx * 8 + 4) = v1;
    }
}

// ---------------------------------------------------------------------------
// Recurrent scan (one layer), fp32. data[Bc][T][H] holds proj on input and is
// overwritten in place with h. Each WG owns 2 batch rows, loops t=0..T-1.
// W_hh streamed through LDS in k-chunks of 16 (44 KB static LDS total).
// h_new[b][n] = relu(proj[b][t][n] + sum_k W[n][k] * h[b][k])
// ---------------------------------------------------------------------------
__global__ __launch_bounds__(256) void scan_kernel(
    float* __restrict__ data, const float* __restrict__ Whh)
{
    __shared__ alignas(16) float Ws[512][20];   // k-chunk of 16, padded to 20 (40 KB)
    __shared__ alignas(16) float hbuf[2][H_];   // 4 KB

    const int tid = threadIdx.x;
    const int b0 = blockIdx.x * 2;   // local batch pair within this chunk
    const int nA = tid;
    const int nB = tid + 256;

    hbuf[0][nA] = 0.f; hbuf[0][nB] = 0.f;
    hbuf[1][nA] = 0.f; hbuf[1][nB] = 0.f;

    for (int t = 0; t < T_; t++) {
        float a00 = 0.f, a01 = 0.f, a10 = 0.f, a11 = 0.f;  // a[b][{nA,nB}]
        for (int kc = 0; kc < 32; kc++) {
            __syncthreads();  // prior compute / hbuf writes done before restage
            // stage W[0..511][kc*16 .. +15]: 2048 float4, 8 per thread
#pragma unroll
            for (int i = 0; i < 8; i++) {
                int f = tid + 256 * i;
                int n = f >> 2, k4 = (f & 3) * 4;
                float4 v = *(const float4*)(Whh + (size_t)n * H_ + kc * 16 + k4);
                *(float4*)&Ws[n][k4] = v;
            }
            __syncthreads();
#pragma unroll
            for (int q = 0; q < 4; q++) {
                float4 h0 = *(const float4*)&hbuf[0][kc * 16 + q * 4];  // broadcast
                float4 h1 = *(const float4*)&hbuf[1][kc * 16 + q * 4];
                float4 wA = *(const float4*)&Ws[nA][q * 4];
                float4 wB = *(const float4*)&Ws[nB][q * 4];
                a00 = fmaf(wA.x, h0.x, a00); a00 = fmaf(wA.y, h0.y, a00);
                a00 = fmaf(wA.z, h0.z, a00); a00 = fmaf(wA.w, h0.w, a00);
                a01 = fmaf(wB.x, h0.x, a01); a01 = fmaf(wB.y, h0.y, a01);
                a01 = fmaf(wB.z, h0.z, a01); a01 = fmaf(wB.w, h0.w, a01);
                a10 = fmaf(wA.x, h1.x, a10); a10 = fmaf(wA.y, h1.y, a10);
                a10 = fmaf(wA.z, h1.z, a10); a10 = fmaf(wA.w, h1.w, a10);
                a11 = fmaf(wB.x, h1.x, a11); a11 = fmaf(wB.y, h1.y, a11);
                a11 = fmaf(wB.z, h1.z, a11); a11 = fmaf(wB.w, h1.w, a11);
            }
        }
        __syncthreads();  // all reads of hbuf/Ws for this step complete

        const size_t base0 = ((size_t)b0 * T_ + t) * H_;
        const size_t base1 = base0 + (size_t)T_ * H_;  // batch row b0+1
        float hA0 = fmaxf(a00 + data[base0 + nA], 0.f);
        float hB0 = fmaxf(a01 + data[base0 + nB], 0.f);
        float hA1 = fmaxf(a10 + data[base1 + nA], 0.f);
        float hB1 = fmaxf(a11 + data[base1 + nB], 0.f);
        data[base0 + nA] = hA0; data[base0 + nB] = hB0;
        data[base1 + nA] = hA1; data[base1 + nB] = hB1;
        hbuf[0][nA] = hA0; hbuf[0][nB] = hB0;
        hbuf[1][nA] = hA1; hbuf[1][nB] = hB1;
        // next iteration's first __syncthreads separates these writes from reads
    }
}

// ---------------------------------------------------------------------------
// FC head: out[b][c] = sum_i h1[b][i] * Wfc[c][i] + bfc[c],  i in [0, T*H)
// One WG per (local) batch row; acc[10] per thread; wave shuffle + LDS reduce.
// ---------------------------------------------------------------------------
__global__ __launch_bounds__(256) void fc_kernel(
    const float* __restrict__ Hl, const float* __restrict__ Wfc,
    const float* __restrict__ bfc, float* __restrict__ out)
{
    const int b = blockIdx.x;
    const int tid = threadIdx.x;
    const float* hb = Hl + (size_t)b * (T_ * H_);

    float acc[C_];
#pragma unroll
    for (int c = 0; c < C_; c++) acc[c] = 0.f;

    for (int i = tid * 4; i < T_ * H_; i += 256 * 4) {
        float4 hv = *(const float4*)(hb + i);
#pragma unroll
        for (int c = 0; c < C_; c++) {
            float4 wv = *(const float4*)(Wfc + (size_t)c * (T_ * H_) + i);
            acc[c] = fmaf(hv.x, wv.x, fmaf(hv.y, wv.y,
                     fmaf(hv.z, wv.z, fmaf(hv.w, wv.w, acc[c]))));
        }
    }

    __shared__ float red[4][C_];
#pragma unroll
    for (int c = 0; c < C_; c++) {
        float v = acc[c];
#pragma unroll
        for (int off = 32; off >= 1; off >>= 1) v += __shfl_xor(v, off, 64);
        if ((tid & 63) == 0) red[tid >> 6][c] = v;
    }
    __syncthreads();
    if (tid < C_) {
        float v = red[0][tid] + red[1][tid] + red[2][tid] + red[3][tid] + bfc[tid];
        out[(size_t)b * C_ + tid] = v;
    }
}

// ---------------------------------------------------------------------------
// Batch-chunked pipeline. Chunk size Bc chosen from ws_size (runtime constant,
// so every call does identical work -> graph-capture safe). Peak scratch use:
// 2 * Bc * T * H * 4 bytes (Bc=256 -> 128 MiB ... Bc=2 -> 1 MiB).
// ---------------------------------------------------------------------------
extern "C" void kernel_launch(void* const* d_in, const int* in_sizes, int n_in,
                              void* d_out, int out_size, void* d_ws, size_t ws_size,
                              hipStream_t stream)
{
    (void)in_sizes; (void)n_in; (void)out_size;

    const float* x    = (const float*)d_in[0];
    const float* Wih0 = (const float*)d_in[1];
    const float* Whh0 = (const float*)d_in[2];
    const float* bih0 = (const float*)d_in[3];
    const float* bhh0 = (const float*)d_in[4];
    const float* Wih1 = (const float*)d_in[5];
    const float* Whh1 = (const float*)d_in[6];
    const float* bih1 = (const float*)d_in[7];
    const float* bhh1 = (const float*)d_in[8];
    const float* Wfc  = (const float*)d_in[9];
    const float* bfc  = (const float*)d_in[10];
    float* out = (float*)d_out;

    const size_t per_row = (size_t)T_ * H_ * sizeof(float);  // 256 KiB / batch row
    int Bc = B_;
    while (Bc > 2 && 2 * (size_t)Bc * per_row > ws_size) Bc >>= 1;

    float* ws0 = (float*)d_ws;                       // [Bc][T][H] proj0 -> h0
    float* ws1 = ws0 + (size_t)Bc * T_ * H_;         // [Bc][T][H] proj1 -> h1

    for (int b0 = 0; b0 < B_; b0 += Bc) {
        const float* xc = x + (size_t)b0 * T_ * F_;
        dim3 gproj(Bc * T_ / 64, H_ / 128);

        // layer 0: proj = x @ Wih0^T + b_ih0 + b_hh0, then scan in place
        gemm_bias_kernel<F_><<<gproj, 256, 0, stream>>>(xc, Wih0, bih0, bhh0, ws0);
        scan_kernel<<<Bc / 2, 256, 0, stream>>>(ws0, Whh0);

        // layer 1
        gemm_bias_kernel<H_><<<gproj, 256, 0, stream>>>(ws0, Wih1, bih1, bhh1, ws1);
        scan_kernel<<<Bc / 2, 256, 0, stream>>>(ws1, Whh1);

        // FC head for this chunk's rows
        fc_kernel<<<Bc, 256, 0, stream>>>(ws1, Wfc, bfc, out + (size_t)b0 * C_);
    }
}